// Round 8
// baseline (184.469 us; speedup 1.0000x reference)
//
#include <hip/hip_runtime.h>
#include <stdint.h>

#define H_ 96
#define W_ 96
#define C_ 256
#define O_ 256
#define N_ 2
#define HW_ (H_*W_)          // 9216
#define M_ (N_*HW_)          // 18432
#define GK 2304              // C_*9

typedef _Float16 f16x8 __attribute__((ext_vector_type(8)));
typedef _Float16 f16x2 __attribute__((ext_vector_type(2)));
typedef float f32x4 __attribute__((ext_vector_type(4)));
typedef unsigned short us4 __attribute__((ext_vector_type(4)));
typedef unsigned short us8 __attribute__((ext_vector_type(8)));

__device__ __forceinline__ unsigned short f2h(float f) {
  union { _Float16 h; unsigned short u; } v;
  v.h = (_Float16)f;
  return v.u;
}
__device__ __forceinline__ f16x2 hpair(float f) {
  const _Float16 h = (_Float16)f;
  return (f16x2){h, h};
}

// ---------------- Kernel 1: combined prep (fp16), unchanged.
__global__ __launch_bounds__(256) void k_pre(const float* __restrict__ x,
                                             const float* __restrict__ w_df,
                                             const float* __restrict__ w_tm,
                                             const float* __restrict__ w_tr,
                                             unsigned short* __restrict__ xt,
                                             unsigned short* __restrict__ wfrag,
                                             unsigned short* __restrict__ w6p) {
  const int b = blockIdx.x;
  const int tid = threadIdx.x;
  if (b < 576) {
    __shared__ unsigned short tile[64][130];
    const int pt = b % 144;          // 144 p-tiles of 64
    const int ch = (b / 144) & 1;    // 2 c-halves of 128
    const int n  = b / 288;
    const int p0 = pt * 64, c0 = ch * 128;
    const float* xp = x + (size_t)n * C_ * HW_;
    unsigned short* xtp = xt + (size_t)n * C_ * HW_;
    const int tx = tid & 15, ty = tid >> 4;  // 16 p-chunks x 16 c-rows
#pragma unroll
    for (int pass = 0; pass < 8; pass++) {
      const int c = pass * 16 + ty;
      const f32x4 v = *(const f32x4*)(xp + (size_t)(c0 + c) * HW_ + p0 + tx * 4);
#pragma unroll
      for (int i = 0; i < 4; i++) tile[tx * 4 + i][c] = f2h(v[i]);
    }
    __syncthreads();
    const int l32 = tid & 31, pr = tid >> 5;  // 32 c-chunks x 8 p-rows
#pragma unroll
    for (int pass = 0; pass < 8; pass++) {
      const int p = pass * 8 + pr;
      us4 v;
#pragma unroll
      for (int i = 0; i < 4; i++) v[i] = tile[p][l32 * 4 + i];
      *(us4*)(xtp + (size_t)(p0 + p) * C_ + c0 + l32 * 4) = v;
    }
  } else if (b < 864) {
    const int base = (b - 576) * 2048 + tid * 8;  // < 589824
    const int l  = (base >> 3) & 63;
    const int g  = (base >> 9) & 15;
    const int ks = (base >> 13) & 7;
    const int t  = base >> 16;
    const int o  = g * 16 + (l & 15);
    const int c  = ks * 32 + (l >> 4) * 8;
    us8 res;
#pragma unroll
    for (int j = 0; j < 8; j++) res[j] = f2h(w_df[(size_t)(o * 256 + c + j) * 9 + t]);
    *(us8*)(wfrag + base) = res;
  } else {
    int idx = (b - 864) * 256 + tid;   // < 9*16*256 = 36864
    int t = idx >> 12;
    int r = idx & 4095;
    int j = r >> 8;
    int c = r & 255;
    float v = 0.f;
    if (j < 4) v = w_tm[(size_t)(j * C_ + c) * 9 + t];
    else if (j < 6) v = w_tr[(size_t)((j - 4) * C_ + c) * 9 + t];
    w6p[idx] = f2h(v);
  }
}

// ---------------- Kernel 2: FUSED offsets + sample + GEMM + BN + res + ReLU.
// v10: N-PAIRED STRIPS. Diagnosis across r0-r7: time is invariant to
// occupancy (15-36%), VALU, barriers (11->3), prefetch -> the bottleneck is
// L2 bandwidth (~1.2GB/dispatch at ~14TB/s eff = 83us; v4's +340MB -> x1.27
// measured; r3's spill -> 140us; all fit). Only reducible term: the B
// (Wfrag) stream = #blocks x 1.18MB. Each block now processes TWO 32-row
// strips, one per image (m0 and m0+9216), sharing every B fragment across
// both strips: grid 576 -> 288, B traffic 663 -> 332MB (total ~880MB).
// Each strip keeps the verified v6 structure (single-h strip, prologue/
// staging/epilogue run per strip). Corner prefetch dropped (VGPR headroom;
// under L2-bound, latency stalls are free). ONE barrier per tap, As
// double-buffered per strip. launch_bounds(512,2): cap 128, LDS 72.6KB ->
// 2 blocks/CU (16 waves). L2 balance is per-XCD (36 blocks/XCD), so the
// 288-block grid stays balanced where it matters.
__global__ __launch_bounds__(512, 2) void k_fused(const unsigned short* __restrict__ xt,
                                                  const unsigned short* __restrict__ Wfrag,
                                                  const unsigned short* __restrict__ w6p,
                                                  const float* __restrict__ b_tm,
                                                  const float* __restrict__ b_tr,
                                                  const float* __restrict__ xres,
                                                  const float* __restrict__ gamma,
                                                  const float* __restrict__ beta,
                                                  const float* __restrict__ mean,
                                                  const float* __restrict__ var,
                                                  float* __restrict__ out) {
  __shared__ unsigned short As[2][2][32 * 256] __attribute__((aligned(16)));  // [buf][strip] 64KB
  __shared__ float sred[8][16][8];            // 4KB
  __shared__ float coords_s[2][32][9][2];     // 4.6KB
  const int tid = threadIdx.x;
  const int wave = tid >> 6, lane = tid & 63;
  const int row = lane & 15, quad = lane >> 4;
  const int bm = (blockIdx.x & 7) * 36 + (blockIdx.x >> 3);  // XCD swizzle, 288=8*36
  const int m0 = bm * 32;        // hw offset WITHIN each image (0..9184)
  const int sr = tid >> 4;       // staging row 0..31
  const int cg = tid & 15;       // staging 16-channel group

  // ---- Prologue: offset conv, run once per strip (s = image index) ----
  for (int s = 0; s < 2; ++s) {
    const unsigned short* xts = xt + (size_t)s * C_ * HW_;
    {
      const int h = m0 / W_;
      const int w0 = m0 - h * W_;  // multiple of 32 -> single-h strip
      const int rh = wave >> 2;    // row half
      const int cq = (wave & 3) * 64;
      f32x4 oacc = {0.f, 0.f, 0.f, 0.f};
      const f16x8 zero8 = {};
#pragma unroll
      for (int t = 0; t < 9; t++) {
        const int ty = t / 3, tx = t % 3;
        const int y = h + ty - 1;
        if (y < 0 || y >= H_) continue;  // wave-uniform
        const int xx = w0 + rh * 16 + row + tx - 1;
        const bool valid = (xx >= 0) && (xx < W_);
        const int xc = min(max(xx, 0), W_ - 1);
        const unsigned short* arow = xts + (size_t)(y * W_ + xc) * C_ + cq + quad * 8;
        const unsigned short* brow = w6p + (size_t)(t * 16 + row) * C_ + cq + quad * 8;
#pragma unroll
        for (int ks = 0; ks < 2; ks++) {
          f16x8 av = *(const f16x8*)(const void*)(arow + ks * 32);
          if (!valid) av = zero8;
          f16x8 bv = *(const f16x8*)(const void*)(brow + ks * 32);
          oacc = __builtin_amdgcn_mfma_f32_16x16x32_f16(av, bv, oacc, 0, 0, 0);
        }
      }
      if (row < 6) {
#pragma unroll
        for (int r = 0; r < 4; r++) sred[wave][quad * 4 + r][row] = oacc[r];
      }
    }
    __syncthreads();
    if (wave < 2 && lane < 16) {
      const int rg = wave * 16 + lane;  // row 0..31
      const int hwm = m0 + rg;
      const int h = hwm / W_, w = hwm - h * W_;
      float a[6];
#pragma unroll
      for (int j = 0; j < 6; j++)
        a[j] = sred[wave * 4 + 0][lane][j] + sred[wave * 4 + 1][lane][j] +
               sred[wave * 4 + 2][lane][j] + sred[wave * 4 + 3][lane][j];
      const float tm0 = a[0] + b_tm[0];
      const float tm1 = a[1] + b_tm[1];
      const float tm2 = a[2] + b_tm[2];
      const float tm3 = a[3] + b_tm[3];
      const float tr0 = a[4] + b_tr[0];
      const float tr1 = a[5] + b_tr[1];
#pragma unroll
      for (int t = 0; t < 9; t++) {
        const float ry = (float)(t / 3) - 1.f;
        const float rx = (float)(t % 3) - 1.f;
        coords_s[s][rg][t][0] = (float)h + tr0 + tm0 * ry + tm1 * rx;
        coords_s[s][rg][t][1] = (float)w + tr1 + tm2 * ry + tm3 * rx;
      }
    }
    __syncthreads();
  }

  // ---- Main loop over 9 taps ----
  f32x4 acc[2][2][2] = {};  // [strip][m-frag][o-frag], fully unrolled indices
  f16x2 cwh0, cwh1, cwh2, cwh3;
  int cb[4];
  us8 u0[4], u1[4];

#define PREP1(TAP, S)                                                          \
  {                                                                            \
    const float py = coords_s[S][sr][TAP][0];                                  \
    const float px = coords_s[S][sr][TAP][1];                                  \
    const float fy = floorf(py), fx = floorf(px);                              \
    const float wy = py - fy, wx = px - fx;                                    \
    const int y0 = (int)fy, x0 = (int)fx;                                      \
    const int y1 = y0 + 1, x1 = x0 + 1;                                        \
    const float vy0 = (y0 >= 0 && y0 < H_) ? 1.f : 0.f;                        \
    const float vy1 = (y1 >= 0 && y1 < H_) ? 1.f : 0.f;                        \
    const float vx0 = (x0 >= 0 && x0 < W_) ? 1.f : 0.f;                        \
    const float vx1 = (x1 >= 0 && x1 < W_) ? 1.f : 0.f;                        \
    cwh0 = hpair((1.f - wy) * (1.f - wx) * vy0 * vx0);                         \
    cwh1 = hpair((1.f - wy) * wx * vy0 * vx1);                                 \
    cwh2 = hpair(wy * (1.f - wx) * vy1 * vx0);                                 \
    cwh3 = hpair(wy * wx * vy1 * vx1);                                         \
    const int cy0 = min(max(y0, 0), H_ - 1), cy1 = min(max(y1, 0), H_ - 1);    \
    const int cx0 = min(max(x0, 0), W_ - 1), cx1 = min(max(x1, 0), W_ - 1);    \
    cb[0] = (cy0 * W_ + cx0) * C_;                                             \
    cb[1] = (cy0 * W_ + cx1) * C_;                                             \
    cb[2] = (cy1 * W_ + cx0) * C_;                                             \
    cb[3] = (cy1 * W_ + cx1) * C_;                                             \
  }

#define LOADC1(XB)                                                             \
  {                                                                            \
    const int cc = cg * 16;                                                    \
    u0[0] = *(const us8*)(XB + cb[0] + cc); u1[0] = *(const us8*)(XB + cb[0] + cc + 8); \
    u0[1] = *(const us8*)(XB + cb[1] + cc); u1[1] = *(const us8*)(XB + cb[1] + cc + 8); \
    u0[2] = *(const us8*)(XB + cb[2] + cc); u1[2] = *(const us8*)(XB + cb[2] + cc + 8); \
    u0[3] = *(const us8*)(XB + cb[3] + cc); u1[3] = *(const us8*)(XB + cb[3] + cc + 8); \
  }

#define LERP8V(DST, U)                                                         \
  {                                                                            \
    const f16x2* p0 = (const f16x2*)&U[0];                                     \
    const f16x2* p1 = (const f16x2*)&U[1];                                     \
    const f16x2* p2 = (const f16x2*)&U[2];                                     \
    const f16x2* p3 = (const f16x2*)&U[3];                                     \
    f16x2* d = (f16x2*)&DST;                                                   \
    _Pragma("unroll")                                                          \
    for (int p = 0; p < 4; p++) {                                              \
      f16x2 r = p0[p] * cwh0;                                                  \
      r = p1[p] * cwh1 + r;                                                    \
      r = p2[p] * cwh2 + r;                                                    \
      r = p3[p] * cwh3 + r;                                                    \
      d[p] = r;                                                                \
    }                                                                          \
  }

  // stage strip S's row sr into As[buf][S] (slot = (q&24)|((q^sr)&7))
#define STAGE(TAP, S, XB)                                                      \
  {                                                                            \
    PREP1(TAP, S);                                                             \
    LOADC1(XB);                                                                \
    unsigned short* asb = &As[(TAP) & 1][S][0];                                \
    const int q0i = cg * 2, q1i = cg * 2 + 1;                                  \
    const int s0 = (q0i & 24) | ((q0i ^ sr) & 7);                              \
    const int s1 = (q1i & 24) | ((q1i ^ sr) & 7);                              \
    us8 r0, r1;                                                                \
    LERP8V(r0, u0);                                                            \
    LERP8V(r1, u1);                                                            \
    *(us8*)(void*)&asb[sr * 256 + s0 * 8] = r0;                                \
    *(us8*)(void*)&asb[sr * 256 + s1 * 8] = r1;                                \
  }

  const unsigned short* xt1 = xt + (size_t)C_ * HW_;

  for (int tap = 0; tap < 9; tap++) {
    // stage both strips (sequential: keeps transient VGPR at one corner set)
    STAGE(tap, 0, xt);
    STAGE(tap, 1, xt1);

    // B frags for ks0 issued before the barrier: L2 latency hides under the
    // other waves' staging; the barrier's vmcnt drain completes them.
    const unsigned short* wfTap =
        Wfrag + (size_t)tap * 65536 + wave * 1024 + lane * 8;
    f16x8 bv[2];
#pragma unroll
    for (int ot = 0; ot < 2; ot++) bv[ot] = *(const f16x8*)(const void*)(wfTap + ot * 512);
    __builtin_amdgcn_sched_barrier(0);

    __syncthreads();  // ONE barrier per tap

    const unsigned short* A0 = &As[tap & 1][0][0];
    const unsigned short* A1 = &As[tap & 1][1][0];
#pragma unroll
    for (int ks = 0; ks < 8; ks++) {
      const int q = ks * 4 + quad;
      const int slot = (q & 24) | ((q ^ row) & 7);
      const f16x8 a00 = *(const f16x8*)(const void*)&A0[row * 256 + slot * 8];
      const f16x8 a01 = *(const f16x8*)(const void*)&A0[(row + 16) * 256 + slot * 8];
      const f16x8 a10 = *(const f16x8*)(const void*)&A1[row * 256 + slot * 8];
      const f16x8 a11 = *(const f16x8*)(const void*)&A1[(row + 16) * 256 + slot * 8];
      f16x8 bn[2];
      if (ks < 7) {
        const unsigned short* wfn = wfTap + (size_t)(ks + 1) * 8192;
#pragma unroll
        for (int ot = 0; ot < 2; ot++) bn[ot] = *(const f16x8*)(const void*)(wfn + ot * 512);
      }
#pragma unroll
      for (int ot = 0; ot < 2; ot++) {
        acc[0][0][ot] = __builtin_amdgcn_mfma_f32_16x16x32_f16(a00, bv[ot], acc[0][0][ot], 0, 0, 0);
        acc[0][1][ot] = __builtin_amdgcn_mfma_f32_16x16x32_f16(a01, bv[ot], acc[0][1][ot], 0, 0, 0);
        acc[1][0][ot] = __builtin_amdgcn_mfma_f32_16x16x32_f16(a10, bv[ot], acc[1][0][ot], 0, 0, 0);
        acc[1][1][ot] = __builtin_amdgcn_mfma_f32_16x16x32_f16(a11, bv[ot], acc[1][1][ot], 0, 0, 0);
      }
      if (ks < 7) {
#pragma unroll
        for (int ot = 0; ot < 2; ot++) bv[ot] = bn[ot];
      }
    }
    // NO trailing barrier: As double-buffered; the next write to As[tap&1]
    // happens after barrier(tap+1), which orders all reads of As[tap&1].
  }

  // ---- Epilogue: BN + residual + ReLU, float4 rows, both strips ----
  const int hwb = m0 + quad * 4;
#pragma unroll
  for (int ot = 0; ot < 2; ot++) {
    const int o = wave * 32 + ot * 16 + row;
    const float sc = rsqrtf(var[o] + 1e-5f) * gamma[o];
    const float bi = beta[o] - mean[o] * sc;
#pragma unroll
    for (int s = 0; s < 2; ++s) {
      const size_t ob0 = (size_t)(s * O_ + o) * HW_ + hwb;
      f32x4 rv = *(const f32x4*)(xres + ob0);
      f32x4 ov;
#pragma unroll
      for (int r = 0; r < 4; r++) ov[r] = fmaxf(acc[s][0][ot][r] * sc + bi + rv[r], 0.f);
      *(f32x4*)(out + ob0) = ov;
      const size_t ob1 = ob0 + 16;
      rv = *(const f32x4*)(xres + ob1);
#pragma unroll
      for (int r = 0; r < 4; r++) ov[r] = fmaxf(acc[s][1][ot][r] * sc + bi + rv[r], 0.f);
      *(f32x4*)(out + ob1) = ov;
    }
  }
}

extern "C" void kernel_launch(void* const* d_in, const int* in_sizes, int n_in,
                              void* d_out, int out_size, void* d_ws, size_t ws_size,
                              hipStream_t stream) {
  const float* x     = (const float*)d_in[0];
  const float* w_tm  = (const float*)d_in[2];
  const float* b_tm  = (const float*)d_in[3];
  const float* w_tr  = (const float*)d_in[4];
  const float* b_tr  = (const float*)d_in[5];
  const float* w_df  = (const float*)d_in[6];
  const float* gamma = (const float*)d_in[7];
  const float* beta  = (const float*)d_in[8];
  const float* mean  = (const float*)d_in[9];
  const float* var   = (const float*)d_in[10];
  float* out = (float*)d_out;

  char* ws = (char*)d_ws;
  unsigned short* xt    = (unsigned short*)(ws);                       //  9,437,184 B
  unsigned short* wfrag = (unsigned short*)(ws + 9437184);             //  1,179,648 B
  unsigned short* w6p   = (unsigned short*)(ws + 9437184 + 1179648);   //     73,728 B

  k_pre<<<1008, 256, 0, stream>>>(x, w_df, w_tm, w_tr, xt, wfrag, w6p);
  k_fused<<<288, 512, 0, stream>>>(xt, wfrag, w6p, b_tm, b_tr, x,
                                   gamma, beta, mean, var, out);
}

// Round 9
// 162.342 us; speedup vs baseline: 1.1363x; 1.1363x over previous
//
#include <hip/hip_runtime.h>
#include <stdint.h>

#define H_ 96
#define W_ 96
#define C_ 256
#define O_ 256
#define N_ 2
#define HW_ (H_*W_)          // 9216
#define M_ (N_*HW_)          // 18432
#define GK 2304              // C_*9

typedef _Float16 f16x8 __attribute__((ext_vector_type(8)));
typedef _Float16 f16x2 __attribute__((ext_vector_type(2)));
typedef float f32x4 __attribute__((ext_vector_type(4)));
typedef unsigned short us4 __attribute__((ext_vector_type(4)));
typedef unsigned short us8 __attribute__((ext_vector_type(8)));

__device__ __forceinline__ unsigned short f2h(float f) {
  union { _Float16 h; unsigned short u; } v;
  v.h = (_Float16)f;
  return v.u;
}
__device__ __forceinline__ f16x2 hpair(float f) {
  const _Float16 h = (_Float16)f;
  return (f16x2){h, h};
}

// ---------------- Kernel 1: combined prep (fp16), unchanged.
__global__ __launch_bounds__(256) void k_pre(const float* __restrict__ x,
                                             const float* __restrict__ w_df,
                                             const float* __restrict__ w_tm,
                                             const float* __restrict__ w_tr,
                                             unsigned short* __restrict__ xt,
                                             unsigned short* __restrict__ wfrag,
                                             unsigned short* __restrict__ w6p) {
  const int b = blockIdx.x;
  const int tid = threadIdx.x;
  if (b < 576) {
    __shared__ unsigned short tile[64][130];
    const int pt = b % 144;          // 144 p-tiles of 64
    const int ch = (b / 144) & 1;    // 2 c-halves of 128
    const int n  = b / 288;
    const int p0 = pt * 64, c0 = ch * 128;
    const float* xp = x + (size_t)n * C_ * HW_;
    unsigned short* xtp = xt + (size_t)n * C_ * HW_;
    const int tx = tid & 15, ty = tid >> 4;  // 16 p-chunks x 16 c-rows
#pragma unroll
    for (int pass = 0; pass < 8; pass++) {
      const int c = pass * 16 + ty;
      const f32x4 v = *(const f32x4*)(xp + (size_t)(c0 + c) * HW_ + p0 + tx * 4);
#pragma unroll
      for (int i = 0; i < 4; i++) tile[tx * 4 + i][c] = f2h(v[i]);
    }
    __syncthreads();
    const int l32 = tid & 31, pr = tid >> 5;  // 32 c-chunks x 8 p-rows
#pragma unroll
    for (int pass = 0; pass < 8; pass++) {
      const int p = pass * 8 + pr;
      us4 v;
#pragma unroll
      for (int i = 0; i < 4; i++) v[i] = tile[p][l32 * 4 + i];
      *(us4*)(xtp + (size_t)(p0 + p) * C_ + c0 + l32 * 4) = v;
    }
  } else if (b < 864) {
    const int base = (b - 576) * 2048 + tid * 8;  // < 589824
    const int l  = (base >> 3) & 63;
    const int g  = (base >> 9) & 15;
    const int ks = (base >> 13) & 7;
    const int t  = base >> 16;
    const int o  = g * 16 + (l & 15);
    const int c  = ks * 32 + (l >> 4) * 8;
    us8 res;
#pragma unroll
    for (int j = 0; j < 8; j++) res[j] = f2h(w_df[(size_t)(o * 256 + c + j) * 9 + t]);
    *(us8*)(wfrag + base) = res;
  } else {
    int idx = (b - 864) * 256 + tid;   // < 9*16*256 = 36864
    int t = idx >> 12;
    int r = idx & 4095;
    int j = r >> 8;
    int c = r & 255;
    float v = 0.f;
    if (j < 4) v = w_tm[(size_t)(j * C_ + c) * 9 + t];
    else if (j < 6) v = w_tr[(size_t)((j - 4) * C_ + c) * 9 + t];
    w6p[idx] = f2h(v);
  }
}

// ---------------- Kernel 2: FUSED offsets + sample + GEMM + BN + res + ReLU.
// v11: GRID=256, ONE BLOCK PER CU, fat(80-row)/thin(64-row) blocks.
// Model fitted to all 9 prior rounds: per-CU vector-load throughput is the
// wall at ~25-30 B/cyc (v0 31, v3 23, v4 26, v8 31, v10 28 B/cyc -- including
// both regressions). B-stream costs 1.15MB PER BLOCK regardless of M, so
// worst-CU bytes = blocks-on-that-CU x (B + corners). v8 put 3 blocks on the
// tail CUs (6.3MB). Here: 128 blocks x 80 rows + 128 x 64 rows = 18432,
// exactly one block per CU -> worst-CU ~3.2MB (x0.51).
// Enabler: 16 | 9216, so every 16-row tile has uniform (n,h) -- the proven
// per-strip logic applies per tile. LDS ~108KB -> 1 block/CU by LDS too.
// Structure per tap: stage rows in 32-row passes -> ONE barrier -> 8 ks of
// {nt ds_reads, rolling B prefetch, 2*nt MFMA}. As double-buffered.
__global__ __launch_bounds__(512, 2) void k_fused(const unsigned short* __restrict__ xt,
                                                  const unsigned short* __restrict__ Wfrag,
                                                  const unsigned short* __restrict__ w6p,
                                                  const float* __restrict__ b_tm,
                                                  const float* __restrict__ b_tr,
                                                  const float* __restrict__ xres,
                                                  const float* __restrict__ gamma,
                                                  const float* __restrict__ beta,
                                                  const float* __restrict__ mean,
                                                  const float* __restrict__ var,
                                                  float* __restrict__ out) {
  __shared__ unsigned short As[2][80 * 256] __attribute__((aligned(16)));  // 80KB
  __shared__ float sred5[5][8][16][8];     // 20.5KB (prologue only)
  __shared__ float coords_s[80][9][2];     // 5.76KB
  __shared__ int   nofs[80];               // per-row xt element offset (n*C*HW)
  const int tid = threadIdx.x;
  const int wave = tid >> 6, lane = tid & 63;
  const int row = lane & 15, quad = lane >> 4;
  // XCD-clustered bijective map: 256 blocks -> pb 0..255, 32 per XCD.
  const int pb = (blockIdx.x & 7) * 32 + (blockIdx.x >> 3);
  const bool fat = pb < 128;
  const int nt = fat ? 5 : 4;              // 16-row tiles in this block
  const int m0 = fat ? pb * 80 : 10240 + (pb - 128) * 64;
  const int sr = tid >> 4;  // staging row-in-pass 0..31
  const int cg = tid & 15;  // staging 16-channel group

  // ---- Prologue: offset conv, per 16-row tile (uniform n,h per tile) ----
#pragma unroll
  for (int t5 = 0; t5 < 5; ++t5) {
    if (t5 < nt) {
      const int ts = m0 + t5 * 16;
      const int nn = ts / HW_;
      const int hw = ts - nn * HW_;
      const int h = hw / W_, w0 = hw - h * W_;  // w0 multiple of 16
      const unsigned short* xts = xt + (size_t)nn * C_ * HW_;
      const int cq = wave * 32;   // 8 waves x 32ch = full K per tap
      f32x4 oacc = {0.f, 0.f, 0.f, 0.f};
      const f16x8 zero8 = {};
#pragma unroll
      for (int t = 0; t < 9; t++) {
        const int ty = t / 3, tx = t % 3;
        const int y = h + ty - 1;
        if (y < 0 || y >= H_) continue;  // tile-uniform
        const int xx = w0 + row + tx - 1;
        const bool valid = (xx >= 0) && (xx < W_);
        const int xc = min(max(xx, 0), W_ - 1);
        f16x8 av = *(const f16x8*)(const void*)(xts + (size_t)(y * W_ + xc) * C_ + cq + quad * 8);
        if (!valid) av = zero8;
        const f16x8 bv = *(const f16x8*)(const void*)(w6p + (size_t)(t * 16 + row) * C_ + cq + quad * 8);
        oacc = __builtin_amdgcn_mfma_f32_16x16x32_f16(av, bv, oacc, 0, 0, 0);
      }
      if (row < 6) {
#pragma unroll
        for (int r = 0; r < 4; r++) sred5[t5][wave][quad * 4 + r][row] = oacc[r];
      }
    }
  }
  __syncthreads();
  if (tid < nt * 16) {
    const int rg = tid;                 // row in block
    const int gm = m0 + rg;
    const int nn = gm / HW_;
    const int hw = gm - nn * HW_;
    const int h = hw / W_, w = hw - h * W_;
    const int tt = rg >> 4, mm = rg & 15;
    float a[6];
#pragma unroll
    for (int j = 0; j < 6; j++) {
      float s = 0.f;
#pragma unroll
      for (int wv = 0; wv < 8; wv++) s += sred5[tt][wv][mm][j];
      a[j] = s;
    }
    const float tm0 = a[0] + b_tm[0];
    const float tm1 = a[1] + b_tm[1];
    const float tm2 = a[2] + b_tm[2];
    const float tm3 = a[3] + b_tm[3];
    const float tr0 = a[4] + b_tr[0];
    const float tr1 = a[5] + b_tr[1];
#pragma unroll
    for (int t = 0; t < 9; t++) {
      const float ry = (float)(t / 3) - 1.f;
      const float rx = (float)(t % 3) - 1.f;
      coords_s[rg][t][0] = (float)h + tr0 + tm0 * ry + tm1 * rx;
      coords_s[rg][t][1] = (float)w + tr1 + tm2 * ry + tm3 * rx;
    }
    nofs[rg] = nn * (C_ * HW_);
  }
  __syncthreads();

  // ---- Main loop over 9 taps ----
  f32x4 acc[5][2] = {};   // [m-tile][o-frag], all indices compile-time
  f16x2 cwh0, cwh1, cwh2, cwh3;
  int cb[4];
  us8 u0[4], u1[4];

  // stage one row R (0..nt*16-1) of tap TAP into asb
#define STAGEROW(R, TAP, ASB)                                                  \
  {                                                                            \
    const int r_ = (R);                                                        \
    const int nof = nofs[r_];                                                  \
    const float py = coords_s[r_][TAP][0];                                     \
    const float px = coords_s[r_][TAP][1];                                     \
    const float fy = floorf(py), fx = floorf(px);                              \
    const float wy = py - fy, wx = px - fx;                                    \
    const int y0 = (int)fy, x0 = (int)fx;                                      \
    const int y1 = y0 + 1, x1 = x0 + 1;                                        \
    const float vy0 = (y0 >= 0 && y0 < H_) ? 1.f : 0.f;                        \
    const float vy1 = (y1 >= 0 && y1 < H_) ? 1.f : 0.f;                        \
    const float vx0 = (x0 >= 0 && x0 < W_) ? 1.f : 0.f;                        \
    const float vx1 = (x1 >= 0 && x1 < W_) ? 1.f : 0.f;                        \
    cwh0 = hpair((1.f - wy) * (1.f - wx) * vy0 * vx0);                         \
    cwh1 = hpair((1.f - wy) * wx * vy0 * vx1);                                 \
    cwh2 = hpair(wy * (1.f - wx) * vy1 * vx0);                                 \
    cwh3 = hpair(wy * wx * vy1 * vx1);                                         \
    const int cy0 = min(max(y0, 0), H_ - 1), cy1 = min(max(y1, 0), H_ - 1);    \
    const int cx0 = min(max(x0, 0), W_ - 1), cx1 = min(max(x1, 0), W_ - 1);    \
    cb[0] = nof + (cy0 * W_ + cx0) * C_;                                       \
    cb[1] = nof + (cy0 * W_ + cx1) * C_;                                       \
    cb[2] = nof + (cy1 * W_ + cx0) * C_;                                       \
    cb[3] = nof + (cy1 * W_ + cx1) * C_;                                       \
    const int cc = cg * 16;                                                    \
    u0[0] = *(const us8*)(xt + cb[0] + cc); u1[0] = *(const us8*)(xt + cb[0] + cc + 8); \
    u0[1] = *(const us8*)(xt + cb[1] + cc); u1[1] = *(const us8*)(xt + cb[1] + cc + 8); \
    u0[2] = *(const us8*)(xt + cb[2] + cc); u1[2] = *(const us8*)(xt + cb[2] + cc + 8); \
    u0[3] = *(const us8*)(xt + cb[3] + cc); u1[3] = *(const us8*)(xt + cb[3] + cc + 8); \
    us8 r0v, r1v;                                                              \
    {                                                                          \
      const f16x2* p0 = (const f16x2*)&u0[0];                                  \
      const f16x2* p1 = (const f16x2*)&u0[1];                                  \
      const f16x2* p2 = (const f16x2*)&u0[2];                                  \
      const f16x2* p3 = (const f16x2*)&u0[3];                                  \
      f16x2* d = (f16x2*)&r0v;                                                 \
      _Pragma("unroll")                                                        \
      for (int p = 0; p < 4; p++) {                                            \
        f16x2 r = p0[p] * cwh0; r = p1[p] * cwh1 + r;                          \
        r = p2[p] * cwh2 + r;   r = p3[p] * cwh3 + r;  d[p] = r;               \
      }                                                                        \
    }                                                                          \
    {                                                                          \
      const f16x2* p0 = (const f16x2*)&u1[0];                                  \
      const f16x2* p1 = (const f16x2*)&u1[1];                                  \
      const f16x2* p2 = (const f16x2*)&u1[2];                                  \
      const f16x2* p3 = (const f16x2*)&u1[3];                                  \
      f16x2* d = (f16x2*)&r1v;                                                 \
      _Pragma("unroll")                                                        \
      for (int p = 0; p < 4; p++) {                                            \
        f16x2 r = p0[p] * cwh0; r = p1[p] * cwh1 + r;                          \
        r = p2[p] * cwh2 + r;   r = p3[p] * cwh3 + r;  d[p] = r;               \
      }                                                                        \
    }                                                                          \
    const int q0i = cg * 2, q1i = cg * 2 + 1;                                  \
    const int s0 = (q0i & 24) | ((q0i ^ r_) & 7);                              \
    const int s1 = (q1i & 24) | ((q1i ^ r_) & 7);                              \
    *(us8*)(void*)&ASB[r_ * 256 + s0 * 8] = r0v;                               \
    *(us8*)(void*)&ASB[r_ * 256 + s1 * 8] = r1v;                               \
  }

  for (int tap = 0; tap < 9; tap++) {
    unsigned short* __restrict__ asb = &As[tap & 1][0];

    // stage rows in 32-row passes (rows r: slot parity uses r&7; readers use
    // row&7 -- equal because 16-row tiles keep r&7 == (lane&15)&7)
    STAGEROW(sr, tap, asb);
    STAGEROW(sr + 32, tap, asb);
    if (fat) {
      if (sr < 16) STAGEROW(sr + 64, tap, asb);
    }

    // B frags for ks0, issued before the barrier (drain overlaps staging)
    const unsigned short* wfTap =
        Wfrag + (size_t)tap * 65536 + wave * 1024 + lane * 8;
    f16x8 bv[2];
#pragma unroll
    for (int ot = 0; ot < 2; ot++) bv[ot] = *(const f16x8*)(const void*)(wfTap + ot * 512);
    __builtin_amdgcn_sched_barrier(0);

    __syncthreads();  // ONE barrier per tap

#pragma unroll
    for (int ks = 0; ks < 8; ks++) {
      const int q = ks * 4 + quad;
      const int slot = (q & 24) | ((q ^ row) & 7);
      f16x8 a0 = *(const f16x8*)(const void*)&asb[(0 * 16 + row) * 256 + slot * 8];
      f16x8 a1 = *(const f16x8*)(const void*)&asb[(1 * 16 + row) * 256 + slot * 8];
      f16x8 a2 = *(const f16x8*)(const void*)&asb[(2 * 16 + row) * 256 + slot * 8];
      f16x8 a3 = *(const f16x8*)(const void*)&asb[(3 * 16 + row) * 256 + slot * 8];
      f16x8 a4;
      if (fat) a4 = *(const f16x8*)(const void*)&asb[(4 * 16 + row) * 256 + slot * 8];
      f16x8 bn[2];
      if (ks < 7) {
        const unsigned short* wfn = wfTap + (size_t)(ks + 1) * 8192;
#pragma unroll
        for (int ot = 0; ot < 2; ot++) bn[ot] = *(const f16x8*)(const void*)(wfn + ot * 512);
      }
#pragma unroll
      for (int ot = 0; ot < 2; ot++) {
        acc[0][ot] = __builtin_amdgcn_mfma_f32_16x16x32_f16(a0, bv[ot], acc[0][ot], 0, 0, 0);
        acc[1][ot] = __builtin_amdgcn_mfma_f32_16x16x32_f16(a1, bv[ot], acc[1][ot], 0, 0, 0);
        acc[2][ot] = __builtin_amdgcn_mfma_f32_16x16x32_f16(a2, bv[ot], acc[2][ot], 0, 0, 0);
        acc[3][ot] = __builtin_amdgcn_mfma_f32_16x16x32_f16(a3, bv[ot], acc[3][ot], 0, 0, 0);
      }
      if (fat) {
#pragma unroll
        for (int ot = 0; ot < 2; ot++)
          acc[4][ot] = __builtin_amdgcn_mfma_f32_16x16x32_f16(a4, bv[ot], acc[4][ot], 0, 0, 0);
      }
      if (ks < 7) {
#pragma unroll
        for (int ot = 0; ot < 2; ot++) bv[ot] = bn[ot];
      }
    }
    // NO trailing barrier: As double-buffered; next write to As[tap&1]
    // happens after barrier(tap+1), which orders all reads of As[tap&1].
  }

  // ---- Epilogue: BN + residual + ReLU, per-tile uniform (n, hw) ----
#pragma unroll
  for (int ot = 0; ot < 2; ot++) {
    const int o = wave * 32 + ot * 16 + row;
    const float sc = rsqrtf(var[o] + 1e-5f) * gamma[o];
    const float bi = beta[o] - mean[o] * sc;
#pragma unroll
    for (int t5 = 0; t5 < 5; t5++) {
      if (t5 < nt) {
        const int ts = m0 + t5 * 16;
        const int nn = ts / HW_;
        const int hw0 = ts - nn * HW_ + quad * 4;
        const size_t ob = (size_t)(nn * O_ + o) * HW_ + hw0;
        const f32x4 rv = *(const f32x4*)(xres + ob);
        f32x4 ov;
#pragma unroll
        for (int r = 0; r < 4; r++) ov[r] = fmaxf(acc[t5][ot][r] * sc + bi + rv[r], 0.f);
        *(f32x4*)(out + ob) = ov;
      }
    }
  }
}

extern "C" void kernel_launch(void* const* d_in, const int* in_sizes, int n_in,
                              void* d_out, int out_size, void* d_ws, size_t ws_size,
                              hipStream_t stream) {
  const float* x     = (const float*)d_in[0];
  const float* w_tm  = (const float*)d_in[2];
  const float* b_tm  = (const float*)d_in[3];
  const float* w_tr  = (const float*)d_in[4];
  const float* b_tr  = (const float*)d_in[5];
  const float* w_df  = (const float*)d_in[6];
  const float* gamma = (const float*)d_in[7];
  const float* beta  = (const float*)d_in[8];
  const float* mean  = (const float*)d_in[9];
  const float* var   = (const float*)d_in[10];
  float* out = (float*)d_out;

  char* ws = (char*)d_ws;
  unsigned short* xt    = (unsigned short*)(ws);                       //  9,437,184 B
  unsigned short* wfrag = (unsigned short*)(ws + 9437184);             //  1,179,648 B
  unsigned short* w6p   = (unsigned short*)(ws + 9437184 + 1179648);   //     73,728 B

  k_pre<<<1008, 256, 0, stream>>>(x, w_df, w_tm, w_tr, xt, wfrag, w6p);
  k_fused<<<256, 512, 0, stream>>>(xt, wfrag, w6p, b_tm, b_tr, x,
                                   gamma, beta, mean, var, out);
}